// Round 8
// baseline (295.307 us; speedup 1.0000x reference)
//
#include <hip/hip_runtime.h>
#include <math.h>

#define N_HITS  65536
#define K_INST  512
#define MARGIN  0.3f
#define MAXB    16
#define NBLK    256               // 16 blocks per batch x 16 batches = 1/CU
#define TPB     512
#define HITS_PB 4096              // per block, 8 per thread

// ---------------------------------------------------------------------------
// R14: ONE kernel. 7 dispatches -> 1. 256 blocks of 512 threads (1/CU,
// guaranteed co-resident) with device-wide spin barriers. Kills inter-kernel
// bubbles, the partials+k_reduce path, triple-reads of sid/iscp, and the
// cp-table global round-trip for repulsion (phase 4 reuses the LDS table
// staged for phase 3). Also: single >80us dispatch finally lands in rocprof
// top-5 above the harness fills -> full counters next round.
// Barrier protocol: g_bar[] zero at module load; last block (g_ctr winner)
// resets g_bar/g_ctr to zero before exit, so every launch starts clean.
// ---------------------------------------------------------------------------
__device__ int    g_cnt[MAXB * K_INST];
__device__ float  g_d2v[MAXB * K_INST];
__device__ float  g_rv [MAXB * K_INST];
__device__ int    g_fcp[MAXB * K_INST];
__device__ float  g_cpbeta[MAXB * K_INST];
__device__ float4 g_cpemb[MAXB * K_INST * 8];
__device__ int    g_pos[MAXB];
__device__ float  g_scp[MAXB], g_sncp[MAXB], g_sbg[MAXB];
__device__ float  g_attr[MAXB], g_rank[MAXB], g_nuq[MAXB], g_rep[MAXB];
__device__ int    g_ctr;
__device__ int    g_bar[4];

__device__ __forceinline__ void gbar(int id) {
    __syncthreads();
    if (threadIdx.x == 0) {
        __threadfence();
        atomicAdd(&g_bar[id], 1);
        while (__hip_atomic_load(&g_bar[id], __ATOMIC_RELAXED,
                                 __HIP_MEMORY_SCOPE_AGENT) < NBLK)
            __builtin_amdgcn_s_sleep(16);
        __threadfence();
    }
    __syncthreads();
}

__global__ __launch_bounds__(TPB, 4) void k_all(
    const float*  __restrict__ beta,
    const float4* __restrict__ embed4,
    const int*    __restrict__ sid_g,
    const int*    __restrict__ iscp_g,
    float* out, int B) {
    __shared__ float4 l_cp[K_INST * 8];   // 64 KB, XOR-swizzled fp32 cp table
    __shared__ float  l_cb[K_INST];       // 2 KB
    __shared__ int    l_cnt[K_INST];      // 2 KB
    __shared__ float  l_r[K_INST];        // 2 KB
    __shared__ float  l_d2[K_INST];       // 2 KB
    __shared__ float  l_red[24];
    __shared__ int    is_last;

    int bi = blockIdx.x, tid = threadIdx.x;
    int b  = bi >> 4;                      // batch
    int q  = bi & 15;                      // sub-block within batch
    size_t bo = (size_t)b * N_HITS;
    int base = q * HITS_PB;
    bool act = (b < B);

    // ---- P0: init global bins (blocks 0..15 cover all 8192 bins) ----
    {
        int i = bi * TPB + tid;
        if (i < MAXB * K_INST) {
            g_cnt[i] = 0; g_d2v[i] = 0.f; g_rv[i] = 0.f; g_fcp[i] = N_HITS;
        }
        if (i < MAXB) {
            g_pos[i] = 0; g_scp[i] = 0.f; g_sncp[i] = 0.f; g_sbg[i] = 0.f;
            g_attr[i] = 0.f; g_rank[i] = 0.f; g_nuq[i] = 0.f; g_rep[i] = 0.f;
        }
    }
    gbar(0);

    // ---- P1: scan slice for cp hits: first_cp + pos count ----
    if (act) {
        int pc = 0;
#pragma unroll
        for (int i = 0; i < HITS_PB / TPB; ++i) {
            int h = base + i * TPB + tid;
            int c = iscp_g[bo + h];
            if (c == 1) {
                ++pc;
                int s = sid_g[bo + h];
                if (s >= 0) atomicMin(&g_fcp[b * K_INST + s], h);
            }
        }
        for (int o = 32; o > 0; o >>= 1) pc += __shfl_down(pc, o);
        if ((tid & 63) == 0 && pc) atomicAdd(&g_pos[b], pc);
    }
    gbar(1);

    // ---- P2: gather this batch's cp rows (32 rows per block) ----
    if (act && tid < 256) {
        int k = q * 32 + (tid >> 3), sub = tid & 7;
        int row = b * K_INST + k;
        int fc = g_fcp[row];
        int safe = min(fc, N_HITS - 1);
        float4 e = embed4[(bo + safe) * 8 + sub];
        g_cpemb[(size_t)row * 8 + sub] = e;
        if (sub == 0) g_cpbeta[row] = beta[bo + safe];
    }
    gbar(2);

    // ---- P3: stage LDS cp table + fused bce/cnt/rank/d2 over 4096 hits ----
    if (act) {
        const float4* cpt = g_cpemb + (size_t)b * K_INST * 8;
#pragma unroll
        for (int it = 0; it < (K_INST * 8) / TPB; ++it) {
            int idx = it * TPB + tid;
            int k = idx >> 3, j = idx & 7;
            l_cp[(k << 3) | (j ^ (k & 7))] = cpt[idx];
        }
        l_cb[tid] = g_cpbeta[b * K_INST + tid];     // TPB == K_INST
        l_cnt[tid] = 0; l_r[tid] = 0.f; l_d2[tid] = 0.f;
    }
    __syncthreads();

    float a_cp = 0.f, a_ncp = 0.f, a_bg = 0.f;
    if (act) {
        int sv[8], cv[8];
        float xv[8];
#pragma unroll
        for (int i = 0; i < 8; ++i) {
            size_t h = bo + base + i * TPB + tid;
            sv[i] = sid_g[h];
            cv[i] = iscp_g[h];
            xv[i] = beta[h];
        }
#pragma unroll
        for (int pp = 0; pp < 4; ++pp) {
            float4 e[2][8];
#pragma unroll
            for (int i = 0; i < 2; ++i) {
                size_t ebase = (bo + base + (pp * 2 + i) * TPB + tid) * 8;
#pragma unroll
                for (int j = 0; j < 8; ++j) e[i][j] = embed4[ebase + j];
            }
#pragma unroll
            for (int i = 0; i < 2; ++i) {
                int hi = pp * 2 + i;
                int s = sv[hi];
                bool cp = (cv[hi] == 1), valid = (s >= 0), noncp = valid && !cp;
                float x = xv[hi];
                float t = __expf(-fabsf(x));
                float bce = fmaxf(x, 0.f) - (cp ? x : 0.f) + __logf(1.f + t);
                if (cp) a_cp += bce; else if (noncp) a_ncp += bce; else a_bg += bce;

                int sc = max(s, 0);
                int rowb = sc << 3, sw = sc & 7;
                float d2 = 0.f;
#pragma unroll
                for (int j = 0; j < 8; ++j) {
                    float4 cc = l_cp[rowb | (j ^ sw)];
                    float dx = e[i][j].x - cc.x, dy = e[i][j].y - cc.y;
                    float dz = e[i][j].z - cc.z, dw = e[i][j].w - cc.w;
                    d2 += dx * dx + dy * dy + dz * dz + dw * dw;
                }
                if (valid) {
                    atomicAdd(&l_cnt[s], cp ? (1 << 20) : 1);
                    atomicAdd(&l_d2[s], d2);
                    if (noncp) {
                        float r = x + MARGIN - l_cb[s];
                        if (r > 0.f) atomicAdd(&l_r[s], r);
                    }
                }
            }
        }

        // block-reduce bce sums (8 waves)
        for (int o = 32; o > 0; o >>= 1) {
            a_cp  += __shfl_down(a_cp, o);
            a_ncp += __shfl_down(a_ncp, o);
            a_bg  += __shfl_down(a_bg, o);
        }
        int wave = tid >> 6;
        if ((tid & 63) == 0) { l_red[wave] = a_cp; l_red[8 + wave] = a_ncp; l_red[16 + wave] = a_bg; }
    }
    __syncthreads();
    if (act) {
        if (tid == 0) {
            float t0 = 0.f, t1 = 0.f, t2 = 0.f;
            for (int w = 0; w < 8; ++w) { t0 += l_red[w]; t1 += l_red[8 + w]; t2 += l_red[16 + w]; }
            atomicAdd(&g_scp[b], t0);
            atomicAdd(&g_sncp[b], t1);
            atomicAdd(&g_sbg[b], t2);
        }
        // merge LDS bins -> global (sparse guard keeps atomic count low)
        int cc = l_cnt[tid]; if (cc) atomicAdd(&g_cnt[b * K_INST + tid], cc);
        float dv = l_d2[tid]; if (dv != 0.f) atomicAdd(&g_d2v[b * K_INST + tid], dv);
        float rv = l_r[tid];  if (rv != 0.f) atomicAdd(&g_rv[b * K_INST + tid], rv);
    }
    gbar(3);

    // ---- P4a: repulsion tile straight from the LDS table ----
    if (act) {
        int sw = tid & 7;
        float4 r0[8];
#pragma unroll
        for (int cc = 0; cc < 8; ++cc) r0[cc] = l_cp[(tid << 3) | (cc ^ sw)];
        float acc = 0.f;
        for (int j = q * 32; j < q * 32 + 32; ++j) {
            int jw = j & 7;
            float d2 = 0.f;
#pragma unroll
            for (int cc = 0; cc < 8; ++cc) {
                float4 ev = l_cp[(j << 3) | (cc ^ jw)];   // wave-uniform: broadcast
                float ax = r0[cc].x - ev.x, ay = r0[cc].y - ev.y;
                float az = r0[cc].z - ev.z, aw = r0[cc].w - ev.w;
                d2 += ax * ax + ay * ay + az * az + aw * aw;
            }
            acc += __expf(-d2);
        }
        for (int o = 32; o > 0; o >>= 1) acc += __shfl_down(acc, o);
        int wave = tid >> 6;
        if ((tid & 63) == 0) l_red[wave] = acc;
    }
    __syncthreads();
    if (act && tid == 0) {
        float t = 0.f;
        for (int w = 0; w < 8; ++w) t += l_red[w];
        atomicAdd(&g_rep[b], t);
    }

    // ---- P4b: finalize 32 bins per block (first wave only) ----
    if (act && tid < 64) {
        bool vld = tid < 32;
        int bin = bi * 32 + (vld ? tid : 0);
        float attr = 0.f, rank = 0.f, uq = 0.f;
        if (vld) {
            int v = g_cnt[bin];
            int ncp = v & 0xFFFFF, cpc = v >> 20;
            int counts = ncp + cpc;
            int fc = g_fcp[bin];
            bool has_cp = fc < N_HITS, exists = counts > 0;
            attr = (has_cp && exists) ? g_d2v[bin] / fmaxf((float)counts, 1.f) : 0.f;
            rank = (cpc == 1 && ncp > 0) ? g_rv[bin] / fmaxf((float)ncp, 1.f) : 0.f;
            uq = exists ? 1.f : 0.f;
        }
        for (int o = 32; o > 0; o >>= 1) {
            attr += __shfl_down(attr, o);
            rank += __shfl_down(rank, o);
            uq   += __shfl_down(uq, o);
        }
        if (tid == 0) {
            if (attr != 0.f) atomicAdd(&g_attr[b], attr);
            if (rank != 0.f) atomicAdd(&g_rank[b], rank);
            if (uq != 0.f)   atomicAdd(&g_nuq[b], uq);
        }
    }

    // ---- final combine: last block computes out[], resets barrier state ----
    __syncthreads();
    if (tid == 0) {
        __threadfence();
        int v = atomicAdd(&g_ctr, 1);
        is_last = (v == NBLK - 1);
    }
    __syncthreads();
    if (is_last) {
        __threadfence();
        if (tid < 64) {
            int bb = tid;
            float loss = 0.f, bl = 0.f, at = 0.f, rp = 0.f;
            if (bb < B) {
                float pos = (float)g_pos[bb];
                float pw = ((float)N_HITS - pos) / (pos + 1e-6f);
                float bce = (pw * g_scp[bb] + g_sncp[bb] + 2.f * g_sbg[bb]) / (float)N_HITS;
                float rank = g_rank[bb] / fmaxf(g_nuq[bb], 1.f);
                bl = bce + 2.f * rank;
                at = g_attr[bb];
                rp = g_rep[bb] / (float)(K_INST * K_INST);
                loss = bl + at + rp;
            }
            for (int o = 32; o > 0; o >>= 1) {
                loss += __shfl_down(loss, o);
                bl   += __shfl_down(bl, o);
                at   += __shfl_down(at, o);
                rp   += __shfl_down(rp, o);
            }
            if (tid == 0) {
                float inv = 1.f / (float)B;
                out[0] = loss * inv;
                out[1] = bl * inv;
                out[2] = at * inv;
                out[3] = rp * inv;
            }
        }
        if (tid == 64) {
            g_ctr = 0;
            g_bar[0] = 0; g_bar[1] = 0; g_bar[2] = 0; g_bar[3] = 0;
        }
    }
}

// ---------------------------------------------------------------------------
extern "C" void kernel_launch(void* const* d_in, const int* in_sizes, int n_in,
                              void* d_out, int out_size, void* d_ws, size_t ws_size,
                              hipStream_t stream) {
    const float*  beta   = (const float*)d_in[0];
    const float*  embed  = (const float*)d_in[1];
    const int*    sid    = (const int*)d_in[2];
    const int*    iscp   = (const int*)d_in[3];
    float* out = (float*)d_out;

    int BN = in_sizes[0];
    int B  = BN / N_HITS;
    if (B > MAXB) B = MAXB;

    (void)d_ws; (void)ws_size;   // workspace unused (fills run regardless)

    k_all<<<NBLK, TPB, 0, stream>>>(beta, (const float4*)embed, sid, iscp,
                                    out, B);
}

// Round 9
// 256.346 us; speedup vs baseline: 1.1520x; 1.1520x over previous
//
#include <hip/hip_runtime.h>
#include <math.h>

#define N_HITS 65536
#define K_INST 512
#define MARGIN 0.3f
#define MAXB   16
#define BPB    32                 // blocks per batch for k_bce and k_d2
#define HITS_PB (N_HITS / BPB)    // 2048 hits per block

// ---------------------------------------------------------------------------
// Scratch in __device__ globals (fills are unconditional; this just avoids
// host memsets and shields scratch from the poison).
// ---------------------------------------------------------------------------
__device__ int     g_cnt[MAXB * K_INST];
__device__ float   g_d2v[MAXB * K_INST];
__device__ float   g_rv [MAXB * K_INST];
__device__ int     g_fcp[MAXB * K_INST];
__device__ float   g_cpbeta[MAXB * K_INST];
__device__ float4  g_cpemb[MAXB * K_INST * 8];   // fp32 rows (repulsion)
__device__ ushort4 g_cpbf[MAXB * K_INST * 8];    // bf16 rows (d2 table)
__device__ int     g_pcc[MAXB * BPB * K_INST];
__device__ float   g_pcr[MAXB * BPB * K_INST];
__device__ float   g_pcd[MAXB * BPB * K_INST];
__device__ int     g_pos[MAXB];
__device__ float   g_scp[MAXB], g_sncp[MAXB], g_sbg[MAXB];
__device__ float   g_attr[MAXB], g_rank[MAXB], g_nuq[MAXB], g_rep[MAXB];
__device__ int     g_ctr;

__device__ __forceinline__ unsigned short f2bf(float f) {
    unsigned u = __float_as_uint(f);
    return (unsigned short)((u + 0x7FFFu + ((u >> 16) & 1u)) >> 16);
}
__device__ __forceinline__ float bf2f(unsigned short h) {
    return __uint_as_float(((unsigned)h) << 16);
}

// ---------------------------------------------------------------------------
__global__ __launch_bounds__(256) void k_init() {
    int i = blockIdx.x * 256 + threadIdx.x;
    if (i < MAXB * K_INST) {
        g_cnt[i] = 0; g_d2v[i] = 0.f; g_rv[i] = 0.f;
        g_fcp[i] = 0x7F7F7F7F;
    }
    if (i < MAXB) {
        g_pos[i] = 0; g_scp[i] = 0.f; g_sncp[i] = 0.f; g_sbg[i] = 0.f;
        g_attr[i] = 0.f; g_rank[i] = 0.f; g_nuq[i] = 0.f; g_rep[i] = 0.f;
    }
    if (i == 0) g_ctr = 0;
}

// ---------------------------------------------------------------------------
__global__ __launch_bounds__(256) void k_scan(
    const int* __restrict__ sid, const int* __restrict__ iscp) {
    int b = blockIdx.y;
    size_t bo = (size_t)b * N_HITS;
    int i = blockIdx.x * 256 + threadIdx.x;
    int stride = gridDim.x * 256;
    for (; i < N_HITS; i += stride) {
        int c = iscp[bo + i];
        if (c == 1) {
            atomicAdd(&g_pos[b], 1);
            int s = sid[bo + i];
            if (s >= 0) atomicMin(&g_fcp[b * K_INST + s], i);
        }
    }
}

// ---------------------------------------------------------------------------
__global__ __launch_bounds__(256) void k_gather(
    const float* __restrict__ beta, const float4* __restrict__ embed4, int B) {
    int g = blockIdx.x * 256 + threadIdx.x;
    int total = B * K_INST * 8;
    if (g >= total) return;
    int row = g >> 3, sub = g & 7;
    int b = row / K_INST;
    int fc = g_fcp[row];
    int safe = min(fc, N_HITS - 1);
    float4 e = embed4[((size_t)b * N_HITS + safe) * 8 + sub];
    g_cpemb[(size_t)row * 8 + sub] = e;
    ushort4 h;
    h.x = f2bf(e.x); h.y = f2bf(e.y); h.z = f2bf(e.z); h.w = f2bf(e.w);
    g_cpbf[(size_t)row * 8 + sub] = h;
    if (sub == 0) g_cpbeta[row] = beta[b * N_HITS + safe];
}

// ---------------------------------------------------------------------------
// Kernel 3a: BCE / counts / ranking (R12 structure, verified).
// ---------------------------------------------------------------------------
__global__ __launch_bounds__(256) void k_bce(
    const float* __restrict__ beta,
    const int* __restrict__ sid_g, const int* __restrict__ iscp_g, int B) {
    __shared__ float l_cb[K_INST];
    __shared__ int   l_cnt[K_INST];
    __shared__ float l_r[K_INST];
    __shared__ float l_red[12];

    int b = blockIdx.y, tid = threadIdx.x;
    size_t bo = (size_t)b * N_HITS;
    int base = blockIdx.x * HITS_PB;

    for (int k = tid; k < K_INST; k += 256) {
        l_cnt[k] = 0; l_r[k] = 0.f;
        l_cb[k] = g_cpbeta[b * K_INST + k];
    }
    __syncthreads();

    float a_cp = 0.f, a_ncp = 0.f, a_bg = 0.f;
    int sv[8], cv[8];
    float xv[8];
#pragma unroll
    for (int i = 0; i < 8; ++i) {
        size_t h = bo + base + i * 256 + tid;
        sv[i] = sid_g[h];
        cv[i] = iscp_g[h];
        xv[i] = beta[h];
    }
#pragma unroll
    for (int i = 0; i < 8; ++i) {
        int s = sv[i];
        bool cp = (cv[i] == 1), valid = (s >= 0), noncp = valid && !cp;
        float x = xv[i];
        float t = __expf(-fabsf(x));
        float bce = fmaxf(x, 0.f) - (cp ? x : 0.f) + __logf(1.f + t);
        if (cp) a_cp += bce; else if (noncp) a_ncp += bce; else a_bg += bce;
        if (valid) {
            atomicAdd(&l_cnt[s], cp ? (1 << 20) : 1);
            if (noncp) {
                float r = x + MARGIN - l_cb[s];
                if (r > 0.f) atomicAdd(&l_r[s], r);
            }
        }
    }

    for (int o = 32; o > 0; o >>= 1) {
        a_cp  += __shfl_down(a_cp, o);
        a_ncp += __shfl_down(a_ncp, o);
        a_bg  += __shfl_down(a_bg, o);
    }
    int wave = tid >> 6;
    if ((tid & 63) == 0) { l_red[wave] = a_cp; l_red[4 + wave] = a_ncp; l_red[8 + wave] = a_bg; }
    __syncthreads();
    if (tid == 0) {
        atomicAdd(&g_scp[b],  l_red[0] + l_red[1] + l_red[2]  + l_red[3]);
        atomicAdd(&g_sncp[b], l_red[4] + l_red[5] + l_red[6]  + l_red[7]);
        atomicAdd(&g_sbg[b],  l_red[8] + l_red[9] + l_red[10] + l_red[11]);
    }
    size_t po = ((size_t)b * BPB + blockIdx.x) * K_INST;
    for (int k = tid; k < K_INST; k += 256) {
        g_pcc[po + k] = l_cnt[k];
        g_pcr[po + k] = l_r[k];
    }
}

// ---------------------------------------------------------------------------
// Kernel 3b: d2, R15 "two-link DS chain" design.
// R14's full counters showed the real bottleneck: <1 outstanding load/CU,
// VALU 8%, 727 cy/hit -- every prior variant kept a 5-deep lgkmcnt-counted
// DS chain per hit (ds_read + 3x ds_bpermute(shfl) + ds_atomic), serialized
// by VGPR collapse. This version: NO shuffles, NO cross-lane. Lane (hit,sub)
// computes a 4-dim partial and atomicAdds it to a per-(s,sub) bin -- per-hit
// DS chain is ds_read -> VALU -> ds_atomic (2 links), independent across
// hits, so lgkmcnt pipelining can overlap them. bf16 table (R0-verified
// accuracy) at pitch 9 + pitch-9 fp32 bins = 55.3 KB LDS -> 2 blocks x 512
// thr = 16 waves/CU (2x R14's TLP). Embed stream is 1 KB/instr coalesced.
// ---------------------------------------------------------------------------
__global__ __launch_bounds__(512, 4) void k_d2(
    const float4* __restrict__ embed4, const int* __restrict__ sid_g, int B) {
    __shared__ ushort4 l_cp[K_INST * 9];   // 36,864 B: row k block j at k*9+(j^(k&7))
    __shared__ float   l_dp[K_INST * 9];   // 18,432 B: partial bin (s, sub) at s*9+sub

    int b = blockIdx.y, tid = threadIdx.x;
    size_t bo = (size_t)b * N_HITS;
    int base = blockIdx.x * HITS_PB;

    {
        const ushort4* cpt = g_cpbf + (size_t)b * K_INST * 8;
        for (int idx = tid; idx < K_INST * 8; idx += 512) {
            int k = idx >> 3, j = idx & 7;
            l_cp[k * 9 + (j ^ (k & 7))] = cpt[idx];
        }
    }
    for (int i = tid; i < K_INST * 9; i += 512) l_dp[i] = 0.f;
    __syncthreads();

    int sub = tid & 7, hgrp = tid >> 3;    // hgrp in [0,64)
#pragma unroll 1
    for (int g = 0; g < 4; ++g) {
        int sv[8];
        float4 e[8];
#pragma unroll
        for (int j = 0; j < 8; ++j) {
            int hit = base + (g * 8 + j) * 64 + hgrp;
            sv[j] = sid_g[bo + hit];
            e[j]  = embed4[(bo + hit) * 8 + sub];
        }
#pragma unroll
        for (int j = 0; j < 8; ++j) {
            int s = sv[j];
            int row = max(s, 0);
            ushort4 h = l_cp[row * 9 + (sub ^ (row & 7))];
            float c0 = bf2f(h.x), c1 = bf2f(h.y), c2 = bf2f(h.z), c3 = bf2f(h.w);
            float dx = e[j].x - c0, dy = e[j].y - c1;
            float dz = e[j].z - c2, dw = e[j].w - c3;
            float q = dx * dx + dy * dy + dz * dz + dw * dw;
            if (s >= 0) atomicAdd(&l_dp[row * 9 + sub], q);
        }
    }

    __syncthreads();
    size_t po = ((size_t)b * BPB + blockIdx.x) * K_INST;
    for (int s2 = tid; s2 < K_INST; s2 += 512) {
        float t = 0.f;
#pragma unroll
        for (int u = 0; u < 8; ++u) t += l_dp[s2 * 9 + u];
        g_pcd[po + s2] = t;
    }
}

// ---------------------------------------------------------------------------
// Kernel 3c: reduce per-block partials (32 sets each).
// ---------------------------------------------------------------------------
__global__ __launch_bounds__(256) void k_reduce() {
    __shared__ int   rc[4][64];
    __shared__ float rd[4][64];
    __shared__ float rr[4][64];
    int kl = threadIdx.x & 63, p4 = threadIdx.x >> 6;
    int bin = blockIdx.x * 64 + kl;
    int b = bin / K_INST, kk = bin % K_INST;
    size_t basep = ((size_t)b * BPB) * K_INST + kk;
    int cs = 0; float ds = 0.f, rs = 0.f;
    for (int p = p4 * 8; p < p4 * 8 + 8; ++p) {
        cs += g_pcc[basep + (size_t)p * K_INST];
        ds += g_pcd[basep + (size_t)p * K_INST];
        rs += g_pcr[basep + (size_t)p * K_INST];
    }
    rc[p4][kl] = cs; rd[p4][kl] = ds; rr[p4][kl] = rs;
    __syncthreads();
    if (p4 == 0) {
        g_cnt[bin] = rc[0][kl] + rc[1][kl] + rc[2][kl] + rc[3][kl];
        g_d2v[bin] = rd[0][kl] + rd[1][kl] + rd[2][kl] + rd[3][kl];
        g_rv[bin]  = rr[0][kl] + rr[1][kl] + rr[2][kl] + rr[3][kl];
    }
}

// ---------------------------------------------------------------------------
__global__ __launch_bounds__(512) void k_tail(float* out, int B) {
    int tid = threadIdx.x;
    int nrep = B * 16;

    if ((int)blockIdx.x < nrep) {
        __shared__ float4 tile[32 * 8];
        __shared__ float red[8];
        int b = blockIdx.x >> 4, t2 = blockIdx.x & 15;
        const float4* base = g_cpemb + (size_t)b * K_INST * 8;
        float4 r0[8];
#pragma unroll
        for (int cc = 0; cc < 8; ++cc) r0[cc] = base[(size_t)tid * 8 + cc];
        if (tid < 256) tile[tid] = base[(size_t)t2 * 256 + tid];
        __syncthreads();
        float acc = 0.f;
        for (int j = 0; j < 32; ++j) {
            float d2 = 0.f;
#pragma unroll
            for (int cc = 0; cc < 8; ++cc) {
                float4 ev = tile[j * 8 + cc];
                float ax = r0[cc].x - ev.x, ay = r0[cc].y - ev.y;
                float az = r0[cc].z - ev.z, aw = r0[cc].w - ev.w;
                d2 += ax * ax + ay * ay + az * az + aw * aw;
            }
            acc += __expf(-d2);
        }
        for (int o = 32; o > 0; o >>= 1) acc += __shfl_down(acc, o);
        if ((tid & 63) == 0) red[tid >> 6] = acc;
        __syncthreads();
        if (tid == 0) {
            float t = 0.f;
            for (int w = 0; w < 8; ++w) t += red[w];
            atomicAdd(&g_rep[b], t);
        }
    } else {
        __shared__ float red2[3][8];
        int b = blockIdx.x - nrep, k = tid;
        int v = g_cnt[b * K_INST + k];
        int ncp = v & 0xFFFFF, cpc = v >> 20;
        int counts = ncp + cpc;
        int fc = g_fcp[b * K_INST + k];
        bool has_cp = fc < N_HITS, exists = counts > 0;
        float segd = g_d2v[b * K_INST + k];
        float attr = (has_cp && exists) ? segd / fmaxf((float)counts, 1.f) : 0.f;
        float rank = (cpc == 1 && ncp > 0) ? g_rv[b * K_INST + k] / fmaxf((float)ncp, 1.f) : 0.f;
        float uq = exists ? 1.f : 0.f;
        for (int o = 32; o > 0; o >>= 1) {
            attr += __shfl_down(attr, o);
            rank += __shfl_down(rank, o);
            uq   += __shfl_down(uq, o);
        }
        if ((k & 63) == 0) { red2[0][k >> 6] = attr; red2[1][k >> 6] = rank; red2[2][k >> 6] = uq; }
        __syncthreads();
        if (k == 0) {
            float a = 0.f, r = 0.f, u = 0.f;
            for (int w = 0; w < 8; ++w) { a += red2[0][w]; r += red2[1][w]; u += red2[2][w]; }
            g_attr[b] = a; g_rank[b] = r; g_nuq[b] = u;
        }
    }

    __shared__ int is_last;
    __syncthreads();
    if (tid == 0) {
        __threadfence();
        int v = atomicAdd(&g_ctr, 1);
        is_last = (v == (int)gridDim.x - 1);
    }
    __syncthreads();
    if (is_last) {
        __threadfence();
        if (tid < 64) {
            int b = tid;
            float loss = 0.f, bl = 0.f, at = 0.f, rp = 0.f;
            if (b < B) {
                float pos = (float)g_pos[b];
                float pw = ((float)N_HITS - pos) / (pos + 1e-6f);
                float bce = (pw * g_scp[b] + g_sncp[b] + 2.f * g_sbg[b]) / (float)N_HITS;
                float rank = g_rank[b] / fmaxf(g_nuq[b], 1.f);
                bl = bce + 2.f * rank;
                at = g_attr[b];
                rp = g_rep[b] / (float)(K_INST * K_INST);
                loss = bl + at + rp;
            }
            for (int o = 32; o > 0; o >>= 1) {
                loss += __shfl_down(loss, o);
                bl   += __shfl_down(bl, o);
                at   += __shfl_down(at, o);
                rp   += __shfl_down(rp, o);
            }
            if (tid == 0) {
                float inv = 1.f / (float)B;
                out[0] = loss * inv;
                out[1] = bl * inv;
                out[2] = at * inv;
                out[3] = rp * inv;
            }
        }
    }
}

// ---------------------------------------------------------------------------
extern "C" void kernel_launch(void* const* d_in, const int* in_sizes, int n_in,
                              void* d_out, int out_size, void* d_ws, size_t ws_size,
                              hipStream_t stream) {
    const float*  beta   = (const float*)d_in[0];
    const float*  embed  = (const float*)d_in[1];
    const int*    sid    = (const int*)d_in[2];
    const int*    iscp   = (const int*)d_in[3];
    float* out = (float*)d_out;

    int BN = in_sizes[0];
    int B  = BN / N_HITS;
    if (B > MAXB) B = MAXB;
    int BK = B * K_INST;

    (void)d_ws; (void)ws_size;

    k_init<<<(MAXB * K_INST + 255) / 256, 256, 0, stream>>>();

    k_scan<<<dim3(32, B), 256, 0, stream>>>(sid, iscp);

    k_gather<<<(BK * 8 + 255) / 256, 256, 0, stream>>>(beta, (const float4*)embed, B);

    k_bce<<<dim3(BPB, B), 256, 0, stream>>>(beta, sid, iscp, B);

    k_d2<<<dim3(BPB, B), 512, 0, stream>>>((const float4*)embed, sid, B);

    k_reduce<<<BK / 64, 256, 0, stream>>>();

    k_tail<<<B * 16 + B, 512, 0, stream>>>(out, B);
}